// Round 4
// baseline (619.192 us; speedup 1.0000x reference)
//
#include <hip/hip_runtime.h>
#include <hip/hip_bf16.h>
#include <cstdint>

#define NN 8192      // N = B*K nodes
#define EE 1024      // E = B*P edges
#define DD 256       // ZDIM
#define KK_SEL 819   // int(0.1 * 8192)

typedef __attribute__((ext_vector_type(4))) int int32x4;

// ---------------------------------------------------------------------------
// Kernel 1: simi[e][n] = dot(hyper_clss[e], x[n])  (fp32, exact, sequential-k
// FMA chain per output -> bit-identical to previous round's simi)
// 128x128 tile, BK=16, 256 threads, 8x8 micro-tile as 2x2 quadrants of 4.
// ---------------------------------------------------------------------------
__global__ __launch_bounds__(256) void simi_gemm(
    const float* __restrict__ x, const int* __restrict__ y,
    const float* __restrict__ hyper, float* __restrict__ simi) {
  __shared__ float As[16][128];  // [k][e-row]
  __shared__ float Bs[16][128];  // [k][n]
  const int tid = threadIdx.x;
  const int bi = blockIdx.y;  // e-tile [0,8)
  const int bj = blockIdx.x;  // n-tile [0,64)
  const int ty = tid >> 4, tx = tid & 15;
  float acc[2][4][2][4] = {};  // [rhalf][ri][chalf][cj]

  const int lr = tid >> 1;       // staging row [0,128)
  const int lk = (tid & 1) * 8;  // k-offset 0 or 8
  const int eg = bi * 128 + lr;
  const int cls = y[eg >> 4];
  const float* arow = hyper + ((size_t)(cls * 16 + (eg & 15))) * DD;
  const float* brow = x + (size_t)(bj * 128 + lr) * DD;

#pragma unroll 1
  for (int k0 = 0; k0 < DD; k0 += 16) {
    const float4 a0 = *(const float4*)(arow + k0 + lk);
    const float4 a1 = *(const float4*)(arow + k0 + lk + 4);
    const float4 b0 = *(const float4*)(brow + k0 + lk);
    const float4 b1 = *(const float4*)(brow + k0 + lk + 4);
    As[lk + 0][lr] = a0.x; As[lk + 1][lr] = a0.y;
    As[lk + 2][lr] = a0.z; As[lk + 3][lr] = a0.w;
    As[lk + 4][lr] = a1.x; As[lk + 5][lr] = a1.y;
    As[lk + 6][lr] = a1.z; As[lk + 7][lr] = a1.w;
    Bs[lk + 0][lr] = b0.x; Bs[lk + 1][lr] = b0.y;
    Bs[lk + 2][lr] = b0.z; Bs[lk + 3][lr] = b0.w;
    Bs[lk + 4][lr] = b1.x; Bs[lk + 5][lr] = b1.y;
    Bs[lk + 6][lr] = b1.z; Bs[lk + 7][lr] = b1.w;
    __syncthreads();
#pragma unroll
    for (int kk = 0; kk < 16; ++kk) {
      const float4 ar0 = *(const float4*)&As[kk][ty * 4];
      const float4 ar1 = *(const float4*)&As[kk][64 + ty * 4];
      const float4 bc0 = *(const float4*)&Bs[kk][tx * 4];
      const float4 bc1 = *(const float4*)&Bs[kk][64 + tx * 4];
      const float av[2][4] = {{ar0.x, ar0.y, ar0.z, ar0.w},
                              {ar1.x, ar1.y, ar1.z, ar1.w}};
      const float bv[2][4] = {{bc0.x, bc0.y, bc0.z, bc0.w},
                              {bc1.x, bc1.y, bc1.z, bc1.w}};
#pragma unroll
      for (int rh = 0; rh < 2; ++rh)
#pragma unroll
        for (int i = 0; i < 4; ++i)
#pragma unroll
          for (int ch = 0; ch < 2; ++ch)
#pragma unroll
            for (int j = 0; j < 4; ++j)
              acc[rh][i][ch][j] += av[rh][i] * bv[ch][j];
    }
    __syncthreads();
  }
#pragma unroll
  for (int rh = 0; rh < 2; ++rh)
#pragma unroll
    for (int i = 0; i < 4; ++i) {
      const int e = bi * 128 + rh * 64 + ty * 4 + i;
#pragma unroll
      for (int ch = 0; ch < 2; ++ch) {
        float4 o = {acc[rh][i][ch][0], acc[rh][i][ch][1],
                    acc[rh][i][ch][2], acc[rh][i][ch][3]};
        *(float4*)&simi[(size_t)e * NN + bj * 128 + ch * 64 + tx * 4] = o;
      }
    }
}

// ---------------------------------------------------------------------------
// Kernel 2: exact radix-select of the 819th largest per edge; DE folded into
// the radix bookkeeping (DE = N - count(<key) - count(==key)).
// ---------------------------------------------------------------------------
__global__ __launch_bounds__(256) void select_thr(
    const float* __restrict__ simi, float* __restrict__ thr, int* __restrict__ DE) {
  const int e = blockIdx.x;
  const float* row = simi + (size_t)e * NN;
  __shared__ unsigned hist[256];
  __shared__ unsigned sh_prefix;
  __shared__ int sh_r, sh_less, sh_eq;
  const int tid = threadIdx.x;
  if (tid == 0) { sh_prefix = 0u; sh_r = NN - KK_SEL; sh_less = 0; sh_eq = 0; }
  __syncthreads();

  for (int pass = 0; pass < 4; ++pass) {
    const int shift = 24 - pass * 8;
    hist[tid] = 0u;
    __syncthreads();
    const unsigned prefix = sh_prefix;
    const unsigned pmask = (pass == 0) ? 0u : (0xFFFFFFFFu << (shift + 8));
    for (int i = tid; i < NN; i += 256) {
      unsigned u = __float_as_uint(row[i]);
      unsigned k = (u & 0x80000000u) ? ~u : (u | 0x80000000u);
      if ((k & pmask) == prefix) atomicAdd(&hist[(k >> shift) & 0xFFu], 1u);
    }
    __syncthreads();
    if (tid == 0) {
      unsigned cum = 0;
      int r = sh_r;
      for (int b = 0; b < 256; ++b) {
        unsigned h = hist[b];
        if (cum + h > (unsigned)r) {
          sh_prefix = sh_prefix | ((unsigned)b << shift);
          sh_r = r - (int)cum;
          sh_less += (int)cum;
          if (pass == 3) sh_eq = (int)h;
          break;
        }
        cum += h;
      }
    }
    __syncthreads();
  }
  if (tid == 0) {
    const unsigned key = sh_prefix;
    const unsigned u = (key & 0x80000000u) ? (key & 0x7FFFFFFFu) : ~key;
    thr[e] = __uint_as_float(u);
    DE[e] = NN - sh_less - sh_eq;
  }
}

// ---------------------------------------------------------------------------
// Kernel 3: H bitmasks (16 u64 per node) + DV2[n] = DV^-0.5
// ---------------------------------------------------------------------------
__global__ __launch_bounds__(256) void build_h(
    const float* __restrict__ simi, const float* __restrict__ thr,
    unsigned long long* __restrict__ Hbits, float* __restrict__ DV2) {
  __shared__ float sthr[EE];
  const int tid = threadIdx.x;
  for (int e = tid; e < EE; e += 256) sthr[e] = thr[e];
  __syncthreads();
  const int n = blockIdx.x * 256 + tid;
  int dv = 0;
#pragma unroll 1
  for (int w = 0; w < 16; ++w) {
    unsigned long long m = 0ull;
#pragma unroll 8
    for (int b = 0; b < 64; ++b) {
      const int e = w * 64 + b;
      const float v = simi[(size_t)e * NN + n];
      m |= ((unsigned long long)(v > sthr[e])) << b;
    }
    Hbits[(size_t)n * 16 + w] = m;
    dv += __popcll(m);
  }
  DV2[n] = 1.0f / sqrtf((float)dv);
}

// ---------------------------------------------------------------------------
// Kernel 3b: expand Hbits -> H8 (i8 0/1, node-major [8192][1024]), coalesced
// ---------------------------------------------------------------------------
__global__ __launch_bounds__(256) void h8_expand(
    const unsigned long long* __restrict__ Hbits, unsigned char* __restrict__ H8) {
  const int idx = blockIdx.x * 256 + threadIdx.x;  // [0, 8192*64)
  const int n = idx >> 6;
  const int c16 = idx & 63;
  const unsigned long long w = Hbits[(size_t)n * 16 + (c16 >> 2)];
  const unsigned int b16 = (unsigned int)((w >> ((c16 & 3) * 16)) & 0xFFFFull);
  uint4 u;
  u.x = ((b16 >> 0) & 1u) | (((b16 >> 1) & 1u) << 8) | (((b16 >> 2) & 1u) << 16) | (((b16 >> 3) & 1u) << 24);
  u.y = ((b16 >> 4) & 1u) | (((b16 >> 5) & 1u) << 8) | (((b16 >> 6) & 1u) << 16) | (((b16 >> 7) & 1u) << 24);
  u.z = ((b16 >> 8) & 1u) | (((b16 >> 9) & 1u) << 8) | (((b16 >> 10) & 1u) << 16) | (((b16 >> 11) & 1u) << 24);
  u.w = ((b16 >> 12) & 1u) | (((b16 >> 13) & 1u) << 8) | (((b16 >> 14) & 1u) << 16) | (((b16 >> 15) & 1u) << 24);
  *(uint4*)(H8 + (size_t)n * EE + c16 * 16) = u;
}

// ---------------------------------------------------------------------------
// Kernel 4: DE mode + exception list
// ---------------------------------------------------------------------------
__global__ __launch_bounds__(256) void mode_exc(
    const int* __restrict__ DE, int* __restrict__ modeInfo,
    int* __restrict__ exc_idx, float* __restrict__ exc_delta) {
  __shared__ unsigned hist[1024];
  __shared__ int s_mode;
  __shared__ int s_cnt;
  const int tid = threadIdx.x;
  for (int i = tid; i < 1024; i += 256) hist[i] = 0u;
  __syncthreads();
  for (int e = tid; e < EE; e += 256) atomicAdd(&hist[DE[e]], 1u);
  __syncthreads();
  if (tid == 0) {
    int best = 1; unsigned bc = 0;
    for (int i = 0; i < 1024; ++i)
      if (hist[i] > bc) { bc = hist[i]; best = i; }
    s_mode = best; s_cnt = 0;
  }
  __syncthreads();
  const int mode = s_mode;
  const float invMode = 1.0f / (float)mode;
  for (int e = tid; e < EE; e += 256) {
    const int de = DE[e];
    if (de != mode) {
      const int idx = atomicAdd(&s_cnt, 1);
      exc_idx[idx] = e;
      exc_delta[idx] = 1.0f / (float)de - invMode;
    }
  }
  __syncthreads();
  if (tid == 0) {
    modeInfo[0] = s_mode;
    modeInfo[1] = s_cnt;
    modeInfo[2] = __float_as_int(invMode);
  }
}

// ---------------------------------------------------------------------------
// Kernel 5: G = DV2 (H H^T ./ DE) DV2 via i8 MFMA, SYMMETRIC: only the 2080
// upper-triangle 128x128 blocks; off-diagonal tiles mirrored through an
// XOR-swizzled LDS transpose (2 halves of 64 rows in the 32 KB staging smem).
// ---------------------------------------------------------------------------
__global__ __launch_bounds__(256) void g_mfma(
    const unsigned char* __restrict__ H8, const float* __restrict__ DV2,
    const int* __restrict__ modeInfo, const int* __restrict__ exc_idx,
    const float* __restrict__ exc_delta,
    const unsigned long long* __restrict__ Hbits, float* __restrict__ G) {
  __shared__ unsigned char smem[32768];
  __shared__ float sDVr[128], sDVc[128];
  unsigned char* As = smem;
  unsigned char* Bs = smem + 16384;

  // triangular block decode: t -> (bi, bj), bi <= bj
  const int t = blockIdx.x;
  int bi = (int)(64.5 - sqrt(64.5 * 64.5 - 2.0 * (double)t));
  while ((bi + 1) * 64 - ((bi + 1) * bi) / 2 <= t) ++bi;
  while (bi * 64 - (bi * (bi - 1)) / 2 > t) --bi;
  const int bj = bi + (t - (bi * 64 - (bi * (bi - 1)) / 2));

  const int tid = threadIdx.x;
  const int lane = tid & 63;
  const int wave = tid >> 6;
  if (tid < 128) sDVr[tid] = DV2[bi * 128 + tid];
  else sDVc[tid - 128] = DV2[bj * 128 + (tid - 128)];

  const unsigned char* Ag = H8 + (size_t)bi * 128 * EE;
  const unsigned char* Bg = H8 + (size_t)bj * 128 * EE;

  int32x4 acc[4][4];
  const int32x4 zero = {0, 0, 0, 0};
#pragma unroll
  for (int m = 0; m < 4; ++m)
#pragma unroll
    for (int n = 0; n < 4; ++n) acc[m][n] = zero;

  const int wr = wave >> 1, wc = wave & 1;

  for (int s = 0; s < 8; ++s) {
    const int kbase = s * 128;
#pragma unroll
    for (int q = 0; q < 4; ++q) {
      const int chunk = wave * 256 + q * 64 + lane;
      const int r = chunk >> 3;
      const int cq = (chunk & 7) * 16;
      const int csrc = cq ^ ((r & 7) << 4);
      __builtin_amdgcn_global_load_lds(
          (const __attribute__((address_space(1))) void*)(Ag + (size_t)r * EE + kbase + csrc),
          (__attribute__((address_space(3))) void*)(As + (wave * 256 + q * 64) * 16),
          16, 0, 0);
      __builtin_amdgcn_global_load_lds(
          (const __attribute__((address_space(1))) void*)(Bg + (size_t)r * EE + kbase + csrc),
          (__attribute__((address_space(3))) void*)(Bs + (wave * 256 + q * 64) * 16),
          16, 0, 0);
    }
    __syncthreads();
#pragma unroll
    for (int ks = 0; ks < 2; ++ks) {
      int32x4 af[4], bf[4];
#pragma unroll
      for (int m = 0; m < 4; ++m) {
        const int r = wr * 64 + m * 16 + (lane & 15);
        const int c = ks * 64 + (lane >> 4) * 16;
        af[m] = *(const int32x4*)&As[r * 128 + (c ^ ((r & 7) << 4))];
      }
#pragma unroll
      for (int n = 0; n < 4; ++n) {
        const int r = wc * 64 + n * 16 + (lane & 15);
        const int c = ks * 64 + (lane >> 4) * 16;
        bf[n] = *(const int32x4*)&Bs[r * 128 + (c ^ ((r & 7) << 4))];
      }
#pragma unroll
      for (int m = 0; m < 4; ++m)
#pragma unroll
        for (int n = 0; n < 4; ++n)
          acc[m][n] = __builtin_amdgcn_mfma_i32_16x16x64_i8(af[m], bf[n], acc[m][n], 0, 0, 0);
    }
    __syncthreads();
  }

  const float invMode = __int_as_float(modeInfo[2]);
  const int NX = modeInfo[1];
  const int l4 = lane >> 4;
  const int lc = lane & 15;

  // normal (upper) tile store
#pragma unroll
  for (int m = 0; m < 4; ++m) {
#pragma unroll
    for (int n = 0; n < 4; ++n) {
#pragma unroll
      for (int reg = 0; reg < 4; ++reg) {
        const int Rl = wr * 64 + m * 16 + l4 * 4 + reg;
        const int Cl = wc * 64 + n * 16 + lc;
        const int Rg = bi * 128 + Rl;
        const int Cg = bj * 128 + Cl;
        float v = (float)acc[m][n][reg] * invMode;
        for (int xx = 0; xx < NX; ++xx) {
          const int e = exc_idx[xx];
          const int w = e >> 6, b = e & 63;
          const unsigned long long rb = Hbits[(size_t)Rg * 16 + w] >> b;
          const unsigned long long cb = Hbits[(size_t)Cg * 16 + w] >> b;
          v += exc_delta[xx] * (float)(rb & cb & 1ull);
        }
        G[(size_t)Rg * NN + Cg] = v * sDVr[Rl] * sDVc[Cl];
      }
    }
  }

  // mirror (lower) tile: transpose through swizzled LDS, 2 halves of 64 rows
  if (bi != bj) {
    float* T = (float*)smem;
#pragma unroll 1
    for (int h = 0; h < 2; ++h) {
      __syncthreads();
      if (wr == h) {
#pragma unroll
        for (int m = 0; m < 4; ++m) {
#pragma unroll
          for (int n = 0; n < 4; ++n) {
#pragma unroll
            for (int reg = 0; reg < 4; ++reg) {
              const int Rh = m * 16 + l4 * 4 + reg;  // row within half [0,64)
              const int Cl = wc * 64 + n * 16 + lc;  // [0,128)
              float v = (float)acc[m][n][reg] * invMode;
              if (NX) {
                const int Rg = bi * 128 + h * 64 + Rh;
                const int Cg = bj * 128 + Cl;
                for (int xx = 0; xx < NX; ++xx) {
                  const int e = exc_idx[xx];
                  const int w = e >> 6, b = e & 63;
                  const unsigned long long rb = Hbits[(size_t)Rg * 16 + w] >> b;
                  const unsigned long long cb = Hbits[(size_t)Cg * 16 + w] >> b;
                  v += exc_delta[xx] * (float)(rb & cb & 1ull);
                }
              }
              // value as the mirrored block would compute: v * dv2[outrow] * dv2[outcol]
              T[Rh * 128 + (Cl ^ ((Rh & 7) << 2))] =
                  v * sDVc[Cl] * sDVr[h * 64 + Rh];
            }
          }
        }
      }
      __syncthreads();
      const int orow = tid >> 1;        // output row within bj-tile [0,128)
      const int ob = (tid & 1) * 32;    // output col base within half [0,32/64)
      float4* dst = (float4*)&G[(size_t)(bj * 128 + orow) * NN + bi * 128 + h * 64 + ob];
#pragma unroll
      for (int i = 0; i < 8; ++i) {
        const int rr = ob + i * 4;
        float4 o;
        o.x = T[(rr + 0) * 128 + (orow ^ (((rr + 0) & 7) << 2))];
        o.y = T[(rr + 1) * 128 + (orow ^ (((rr + 1) & 7) << 2))];
        o.z = T[(rr + 2) * 128 + (orow ^ (((rr + 2) & 7) << 2))];
        o.w = T[(rr + 3) * 128 + (orow ^ (((rr + 3) & 7) << 2))];
        dst[i] = o;
      }
    }
  }
}

// ---------------------------------------------------------------------------
extern "C" void kernel_launch(void* const* d_in, const int* in_sizes, int n_in,
                              void* d_out, int out_size, void* d_ws, size_t ws_size,
                              hipStream_t stream) {
  const float* x = (const float*)d_in[0];        // [64,128,256]
  const int* y = (const int*)d_in[1];            // [64]
  const float* hyper = (const float*)d_in[2];    // [100,16,256]
  float* out = (float*)d_out;                    // G [8192*8192] then hyper_x [8192*256]

  float* simi = out;                                              // 32 MB in G region
  unsigned char* H8 = (unsigned char*)(out + (size_t)NN * NN);    // 8 MB in hyper_x slot

  uint8_t* w8 = (uint8_t*)d_ws;
  float* thr = (float*)(w8 + 0);
  int* DE = (int*)(w8 + 4096);
  float* DV2 = (float*)(w8 + 8192);
  int* modeInfo = (int*)(w8 + 40960);
  int* exc_idx = (int*)(w8 + 41984);
  float* exc_delta = (float*)(w8 + 46080);
  unsigned long long* Hbits = (unsigned long long*)(w8 + 65536);

  simi_gemm<<<dim3(NN / 128, EE / 128), 256, 0, stream>>>(x, y, hyper, simi);
  select_thr<<<dim3(EE), 256, 0, stream>>>(simi, thr, DE);
  build_h<<<dim3(NN / 256), 256, 0, stream>>>(simi, thr, Hbits, DV2);
  h8_expand<<<dim3(NN * 64 / 256), 256, 0, stream>>>(Hbits, H8);
  mode_exc<<<dim3(1), 256, 0, stream>>>(DE, modeInfo, exc_idx, exc_delta);
  g_mfma<<<dim3(2080), 256, 0, stream>>>(H8, DV2, modeInfo, exc_idx, exc_delta,
                                         Hbits, out);
  hipMemcpyAsync(out + (size_t)NN * NN, x, (size_t)NN * DD * sizeof(float),
                 hipMemcpyDeviceToDevice, stream);
}

// Round 7
// 511.856 us; speedup vs baseline: 1.2097x; 1.2097x over previous
//
#include <hip/hip_runtime.h>
#include <hip/hip_bf16.h>
#include <cstdint>

#define NN 8192      // N = B*K nodes
#define EE 1024      // E = B*P edges
#define DD 256       // ZDIM
#define KK_SEL 819   // int(0.1 * 8192)

typedef __attribute__((ext_vector_type(4))) int int32x4;

// ---------------------------------------------------------------------------
// Kernel 1: simi[e][n] = dot(hyper_clss[e], x[n])  (fp32, exact, sequential-k
// FMA chain per output -> bit-identical across rounds)
// 128x128 tile, BK=16, 256 threads, 8x8 micro-tile as 2x2 quadrants of 4.
// ---------------------------------------------------------------------------
__global__ __launch_bounds__(256) void simi_gemm(
    const float* __restrict__ x, const int* __restrict__ y,
    const float* __restrict__ hyper, float* __restrict__ simi) {
  __shared__ float As[16][128];  // [k][e-row]
  __shared__ float Bs[16][128];  // [k][n]
  const int tid = threadIdx.x;
  const int bi = blockIdx.y;  // e-tile [0,8)
  const int bj = blockIdx.x;  // n-tile [0,64)
  const int ty = tid >> 4, tx = tid & 15;
  float acc[2][4][2][4] = {};  // [rhalf][ri][chalf][cj]

  const int lr = tid >> 1;       // staging row [0,128)
  const int lk = (tid & 1) * 8;  // k-offset 0 or 8
  const int eg = bi * 128 + lr;
  const int cls = y[eg >> 4];
  const float* arow = hyper + ((size_t)(cls * 16 + (eg & 15))) * DD;
  const float* brow = x + (size_t)(bj * 128 + lr) * DD;

#pragma unroll 1
  for (int k0 = 0; k0 < DD; k0 += 16) {
    const float4 a0 = *(const float4*)(arow + k0 + lk);
    const float4 a1 = *(const float4*)(arow + k0 + lk + 4);
    const float4 b0 = *(const float4*)(brow + k0 + lk);
    const float4 b1 = *(const float4*)(brow + k0 + lk + 4);
    As[lk + 0][lr] = a0.x; As[lk + 1][lr] = a0.y;
    As[lk + 2][lr] = a0.z; As[lk + 3][lr] = a0.w;
    As[lk + 4][lr] = a1.x; As[lk + 5][lr] = a1.y;
    As[lk + 6][lr] = a1.z; As[lk + 7][lr] = a1.w;
    Bs[lk + 0][lr] = b0.x; Bs[lk + 1][lr] = b0.y;
    Bs[lk + 2][lr] = b0.z; Bs[lk + 3][lr] = b0.w;
    Bs[lk + 4][lr] = b1.x; Bs[lk + 5][lr] = b1.y;
    Bs[lk + 6][lr] = b1.z; Bs[lk + 7][lr] = b1.w;
    __syncthreads();
#pragma unroll
    for (int kk = 0; kk < 16; ++kk) {
      const float4 ar0 = *(const float4*)&As[kk][ty * 4];
      const float4 ar1 = *(const float4*)&As[kk][64 + ty * 4];
      const float4 bc0 = *(const float4*)&Bs[kk][tx * 4];
      const float4 bc1 = *(const float4*)&Bs[kk][64 + tx * 4];
      const float av[2][4] = {{ar0.x, ar0.y, ar0.z, ar0.w},
                              {ar1.x, ar1.y, ar1.z, ar1.w}};
      const float bv[2][4] = {{bc0.x, bc0.y, bc0.z, bc0.w},
                              {bc1.x, bc1.y, bc1.z, bc1.w}};
#pragma unroll
      for (int rh = 0; rh < 2; ++rh)
#pragma unroll
        for (int i = 0; i < 4; ++i)
#pragma unroll
          for (int ch = 0; ch < 2; ++ch)
#pragma unroll
            for (int j = 0; j < 4; ++j)
              acc[rh][i][ch][j] += av[rh][i] * bv[ch][j];
    }
    __syncthreads();
  }
#pragma unroll
  for (int rh = 0; rh < 2; ++rh)
#pragma unroll
    for (int i = 0; i < 4; ++i) {
      const int e = bi * 128 + rh * 64 + ty * 4 + i;
#pragma unroll
      for (int ch = 0; ch < 2; ++ch) {
        float4 o = {acc[rh][i][ch][0], acc[rh][i][ch][1],
                    acc[rh][i][ch][2], acc[rh][i][ch][3]};
        *(float4*)&simi[(size_t)e * NN + bj * 128 + ch * 64 + tx * 4] = o;
      }
    }
}

// ---------------------------------------------------------------------------
// Kernel 2: exact radix-select of the 819th largest per edge + DE, with the
// row cached once in LDS as transformed keys; 4 radix passes run from LDS;
// parallel (Hillis-Steele) bin scan replaces the serial tid==0 loop.
// Bit-identical results to the global-memory version.
// ---------------------------------------------------------------------------
__global__ __launch_bounds__(256) void select_thr(
    const float* __restrict__ simi, float* __restrict__ thr, int* __restrict__ DE) {
  __shared__ unsigned keys[NN];   // 32 KB
  __shared__ unsigned hist[256];  // counting + in-place scan
  __shared__ unsigned sh_prefix;
  __shared__ int sh_r, sh_less, sh_eq;
  const int e = blockIdx.x;
  const float* row = simi + (size_t)e * NN;
  const int tid = threadIdx.x;

  // stage + transform: ascending order-preserving uint keys
#pragma unroll
  for (int j = 0; j < 8; ++j) {
    const int idx = (j * 256 + tid) * 4;
    const float4 v = *(const float4*)&row[idx];
    uint4 t;
    unsigned u;
    u = __float_as_uint(v.x); t.x = (u & 0x80000000u) ? ~u : (u | 0x80000000u);
    u = __float_as_uint(v.y); t.y = (u & 0x80000000u) ? ~u : (u | 0x80000000u);
    u = __float_as_uint(v.z); t.z = (u & 0x80000000u) ? ~u : (u | 0x80000000u);
    u = __float_as_uint(v.w); t.w = (u & 0x80000000u) ? ~u : (u | 0x80000000u);
    *(uint4*)&keys[idx] = t;
  }
  if (tid == 0) { sh_prefix = 0u; sh_r = NN - KK_SEL; sh_less = 0; sh_eq = 0; }
  __syncthreads();

  for (int pass = 0; pass < 4; ++pass) {
    const int shift = 24 - pass * 8;
    hist[tid] = 0u;
    __syncthreads();
    const unsigned prefix = sh_prefix;
    const int r = sh_r;
    const unsigned pmask = (pass == 0) ? 0u : (0xFFFFFFFFu << (shift + 8));
#pragma unroll
    for (int j = 0; j < 8; ++j) {
      const uint4 kv = *(const uint4*)&keys[(j * 256 + tid) * 4];
      if ((kv.x & pmask) == prefix) atomicAdd(&hist[(kv.x >> shift) & 0xFFu], 1u);
      if ((kv.y & pmask) == prefix) atomicAdd(&hist[(kv.y >> shift) & 0xFFu], 1u);
      if ((kv.z & pmask) == prefix) atomicAdd(&hist[(kv.z >> shift) & 0xFFu], 1u);
      if ((kv.w & pmask) == prefix) atomicAdd(&hist[(kv.w >> shift) & 0xFFu], 1u);
    }
    __syncthreads();
    const unsigned h = hist[tid];
    // inclusive scan over 256 bins, in place
#pragma unroll
    for (int off = 1; off < 256; off <<= 1) {
      const unsigned add = (tid >= off) ? hist[tid - off] : 0u;
      __syncthreads();
      hist[tid] += add;
      __syncthreads();
    }
    const unsigned inc = hist[tid];
    const unsigned exc = inc - h;
    if ((int)exc <= r && r < (int)inc) {  // exactly one winner (h > 0 there)
      sh_prefix = prefix | ((unsigned)tid << shift);
      sh_r = r - (int)exc;
      sh_less += (int)exc;
      if (pass == 3) sh_eq = (int)h;
    }
    __syncthreads();
  }
  if (tid == 0) {
    const unsigned key = sh_prefix;
    const unsigned u = (key & 0x80000000u) ? (key & 0x7FFFFFFFu) : ~key;
    thr[e] = __uint_as_float(u);
    DE[e] = NN - sh_less - sh_eq;
  }
}

// ---------------------------------------------------------------------------
// Kernel 3: fused H bitmasks + H8 expand + partial DV.
// grid (32, 8): block (nblk, by) handles nodes [nblk*256, +256) x edges
// [by*128, +128) (i.e. Hbits words by*2, by*2+1). DVpart[by][n] = partial
// popcount; summed (integer-exact) in g_mfma's preamble.
// ---------------------------------------------------------------------------
__global__ __launch_bounds__(256) void build_h8(
    const float* __restrict__ simi, const float* __restrict__ thr,
    unsigned long long* __restrict__ Hbits, int* __restrict__ DVpart,
    unsigned char* __restrict__ H8) {
  __shared__ float sthr[128];
  const int tid = threadIdx.x;
  const int nblk = blockIdx.x;
  const int by = blockIdx.y;
  const int e0 = by * 128;
  if (tid < 128) sthr[tid] = thr[e0 + tid];
  __syncthreads();
  const int n = nblk * 256 + tid;
  int dv = 0;
#pragma unroll 1
  for (int w2 = 0; w2 < 2; ++w2) {
    const int w = by * 2 + w2;
    unsigned long long m = 0ull;
#pragma unroll 8
    for (int b = 0; b < 64; ++b) {
      const int el = w2 * 64 + b;
      const float v = simi[(size_t)(e0 + el) * NN + n];
      m |= ((unsigned long long)(v > sthr[el])) << b;
    }
    Hbits[(size_t)n * 16 + w] = m;
    dv += __popcll(m);
#pragma unroll
    for (int jq = 0; jq < 4; ++jq) {
      const unsigned b16 = (unsigned)((m >> (jq * 16)) & 0xFFFFull);
      uint4 u;
      u.x = ((b16 >> 0) & 1u) | (((b16 >> 1) & 1u) << 8) | (((b16 >> 2) & 1u) << 16) | (((b16 >> 3) & 1u) << 24);
      u.y = ((b16 >> 4) & 1u) | (((b16 >> 5) & 1u) << 8) | (((b16 >> 6) & 1u) << 16) | (((b16 >> 7) & 1u) << 24);
      u.z = ((b16 >> 8) & 1u) | (((b16 >> 9) & 1u) << 8) | (((b16 >> 10) & 1u) << 16) | (((b16 >> 11) & 1u) << 24);
      u.w = ((b16 >> 12) & 1u) | (((b16 >> 13) & 1u) << 8) | (((b16 >> 14) & 1u) << 16) | (((b16 >> 15) & 1u) << 24);
      *(uint4*)(H8 + (size_t)n * EE + w * 64 + jq * 16) = u;
    }
  }
  DVpart[by * NN + n] = dv;
}

// ---------------------------------------------------------------------------
// Kernel 4: DE mode + exception list
// ---------------------------------------------------------------------------
__global__ __launch_bounds__(256) void mode_exc(
    const int* __restrict__ DE, int* __restrict__ modeInfo,
    int* __restrict__ exc_idx, float* __restrict__ exc_delta) {
  __shared__ unsigned hist[1024];
  __shared__ int s_mode;
  __shared__ int s_cnt;
  const int tid = threadIdx.x;
  for (int i = tid; i < 1024; i += 256) hist[i] = 0u;
  __syncthreads();
  for (int e = tid; e < EE; e += 256) atomicAdd(&hist[DE[e]], 1u);
  __syncthreads();
  if (tid == 0) {
    int best = 1; unsigned bc = 0;
    for (int i = 0; i < 1024; ++i)
      if (hist[i] > bc) { bc = hist[i]; best = i; }
    s_mode = best; s_cnt = 0;
  }
  __syncthreads();
  const int mode = s_mode;
  const float invMode = 1.0f / (float)mode;
  for (int e = tid; e < EE; e += 256) {
    const int de = DE[e];
    if (de != mode) {
      const int idx = atomicAdd(&s_cnt, 1);
      exc_idx[idx] = e;
      exc_delta[idx] = 1.0f / (float)de - invMode;
    }
  }
  __syncthreads();
  if (tid == 0) {
    modeInfo[0] = s_mode;
    modeInfo[1] = s_cnt;
    modeInfo[2] = __float_as_int(invMode);
  }
}

// ---------------------------------------------------------------------------
// Kernel 5: G = DV2 (H H^T ./ DE) DV2 via i8 MFMA, symmetric (2080 upper
// blocks + mirrored stores through swizzled LDS). DV2 recomputed from the 8
// integer partials with the identical 1.0f/sqrtf expression.
// ---------------------------------------------------------------------------
__global__ __launch_bounds__(256) void g_mfma(
    const unsigned char* __restrict__ H8, const int* __restrict__ DVpart,
    const int* __restrict__ modeInfo, const int* __restrict__ exc_idx,
    const float* __restrict__ exc_delta,
    const unsigned long long* __restrict__ Hbits, float* __restrict__ G) {
  __shared__ unsigned char smem[32768];
  __shared__ float sDVr[128], sDVc[128];
  unsigned char* As = smem;
  unsigned char* Bs = smem + 16384;

  // triangular block decode: t -> (bi, bj), bi <= bj
  const int t = blockIdx.x;
  int bi = (int)(64.5 - sqrt(64.5 * 64.5 - 2.0 * (double)t));
  while ((bi + 1) * 64 - ((bi + 1) * bi) / 2 <= t) ++bi;
  while (bi * 64 - (bi * (bi - 1)) / 2 > t) --bi;
  const int bj = bi + (t - (bi * 64 - (bi * (bi - 1)) / 2));

  const int tid = threadIdx.x;
  const int lane = tid & 63;
  const int wave = tid >> 6;
  if (tid < 128) {
    int dv = 0;
#pragma unroll
    for (int s = 0; s < 8; ++s) dv += DVpart[s * NN + bi * 128 + tid];
    sDVr[tid] = 1.0f / sqrtf((float)dv);
  } else {
    int dv = 0;
#pragma unroll
    for (int s = 0; s < 8; ++s) dv += DVpart[s * NN + bj * 128 + (tid - 128)];
    sDVc[tid - 128] = 1.0f / sqrtf((float)dv);
  }

  const unsigned char* Ag = H8 + (size_t)bi * 128 * EE;
  const unsigned char* Bg = H8 + (size_t)bj * 128 * EE;

  int32x4 acc[4][4];
  const int32x4 zero = {0, 0, 0, 0};
#pragma unroll
  for (int m = 0; m < 4; ++m)
#pragma unroll
    for (int n = 0; n < 4; ++n) acc[m][n] = zero;

  const int wr = wave >> 1, wc = wave & 1;

  for (int s = 0; s < 8; ++s) {
    const int kbase = s * 128;
#pragma unroll
    for (int q = 0; q < 4; ++q) {
      const int chunk = wave * 256 + q * 64 + lane;
      const int r = chunk >> 3;
      const int cq = (chunk & 7) * 16;
      const int csrc = cq ^ ((r & 7) << 4);
      __builtin_amdgcn_global_load_lds(
          (const __attribute__((address_space(1))) void*)(Ag + (size_t)r * EE + kbase + csrc),
          (__attribute__((address_space(3))) void*)(As + (wave * 256 + q * 64) * 16),
          16, 0, 0);
      __builtin_amdgcn_global_load_lds(
          (const __attribute__((address_space(1))) void*)(Bg + (size_t)r * EE + kbase + csrc),
          (__attribute__((address_space(3))) void*)(Bs + (wave * 256 + q * 64) * 16),
          16, 0, 0);
    }
    __syncthreads();
#pragma unroll
    for (int ks = 0; ks < 2; ++ks) {
      int32x4 af[4], bf[4];
#pragma unroll
      for (int m = 0; m < 4; ++m) {
        const int r = wr * 64 + m * 16 + (lane & 15);
        const int c = ks * 64 + (lane >> 4) * 16;
        af[m] = *(const int32x4*)&As[r * 128 + (c ^ ((r & 7) << 4))];
      }
#pragma unroll
      for (int n = 0; n < 4; ++n) {
        const int r = wc * 64 + n * 16 + (lane & 15);
        const int c = ks * 64 + (lane >> 4) * 16;
        bf[n] = *(const int32x4*)&Bs[r * 128 + (c ^ ((r & 7) << 4))];
      }
#pragma unroll
      for (int m = 0; m < 4; ++m)
#pragma unroll
        for (int n = 0; n < 4; ++n)
          acc[m][n] = __builtin_amdgcn_mfma_i32_16x16x64_i8(af[m], bf[n], acc[m][n], 0, 0, 0);
    }
    __syncthreads();
  }

  const float invMode = __int_as_float(modeInfo[2]);
  const int NX = modeInfo[1];
  const int l4 = lane >> 4;
  const int lc = lane & 15;

  // normal (upper) tile store
#pragma unroll
  for (int m = 0; m < 4; ++m) {
#pragma unroll
    for (int n = 0; n < 4; ++n) {
#pragma unroll
      for (int reg = 0; reg < 4; ++reg) {
        const int Rl = wr * 64 + m * 16 + l4 * 4 + reg;
        const int Cl = wc * 64 + n * 16 + lc;
        const int Rg = bi * 128 + Rl;
        const int Cg = bj * 128 + Cl;
        float v = (float)acc[m][n][reg] * invMode;
        for (int xx = 0; xx < NX; ++xx) {
          const int e = exc_idx[xx];
          const int w = e >> 6, b = e & 63;
          const unsigned long long rb = Hbits[(size_t)Rg * 16 + w] >> b;
          const unsigned long long cb = Hbits[(size_t)Cg * 16 + w] >> b;
          v += exc_delta[xx] * (float)(rb & cb & 1ull);
        }
        G[(size_t)Rg * NN + Cg] = v * sDVr[Rl] * sDVc[Cl];
      }
    }
  }

  // mirror (lower) tile: transpose through swizzled LDS, 2 halves of 64 rows
  if (bi != bj) {
    float* T = (float*)smem;
#pragma unroll 1
    for (int h = 0; h < 2; ++h) {
      __syncthreads();
      if (wr == h) {
#pragma unroll
        for (int m = 0; m < 4; ++m) {
#pragma unroll
          for (int n = 0; n < 4; ++n) {
#pragma unroll
            for (int reg = 0; reg < 4; ++reg) {
              const int Rh = m * 16 + l4 * 4 + reg;  // row within half [0,64)
              const int Cl = wc * 64 + n * 16 + lc;  // [0,128)
              float v = (float)acc[m][n][reg] * invMode;
              if (NX) {
                const int Rg = bi * 128 + h * 64 + Rh;
                const int Cg = bj * 128 + Cl;
                for (int xx = 0; xx < NX; ++xx) {
                  const int e = exc_idx[xx];
                  const int w = e >> 6, b = e & 63;
                  const unsigned long long rb = Hbits[(size_t)Rg * 16 + w] >> b;
                  const unsigned long long cb = Hbits[(size_t)Cg * 16 + w] >> b;
                  v += exc_delta[xx] * (float)(rb & cb & 1ull);
                }
              }
              T[Rh * 128 + (Cl ^ ((Rh & 7) << 2))] =
                  v * sDVc[Cl] * sDVr[h * 64 + Rh];
            }
          }
        }
      }
      __syncthreads();
      const int orow = tid >> 1;
      const int ob = (tid & 1) * 32;
      float4* dst = (float4*)&G[(size_t)(bj * 128 + orow) * NN + bi * 128 + h * 64 + ob];
#pragma unroll
      for (int i = 0; i < 8; ++i) {
        const int rr = ob + i * 4;
        float4 o;
        o.x = T[(rr + 0) * 128 + (orow ^ (((rr + 0) & 7) << 2))];
        o.y = T[(rr + 1) * 128 + (orow ^ (((rr + 1) & 7) << 2))];
        o.z = T[(rr + 2) * 128 + (orow ^ (((rr + 2) & 7) << 2))];
        o.w = T[(rr + 3) * 128 + (orow ^ (((rr + 3) & 7) << 2))];
        dst[i] = o;
      }
    }
  }
}

// ---------------------------------------------------------------------------
extern "C" void kernel_launch(void* const* d_in, const int* in_sizes, int n_in,
                              void* d_out, int out_size, void* d_ws, size_t ws_size,
                              hipStream_t stream) {
  const float* x = (const float*)d_in[0];        // [64,128,256]
  const int* y = (const int*)d_in[1];            // [64]
  const float* hyper = (const float*)d_in[2];    // [100,16,256]
  float* out = (float*)d_out;                    // G [8192*8192] then hyper_x [8192*256]

  float* simi = out;                                              // 32 MB in G region
  unsigned char* H8 = (unsigned char*)(out + (size_t)NN * NN);    // 8 MB in hyper_x slot

  uint8_t* w8 = (uint8_t*)d_ws;
  float* thr = (float*)(w8 + 0);                       // 4 KB
  int* DE = (int*)(w8 + 4096);                         // 4 KB
  int* DVpart = (int*)(w8 + 8192);                     // 8*8192*4 = 256 KB
  int* modeInfo = (int*)(w8 + 270336);                 // 16 B
  int* exc_idx = (int*)(w8 + 271360);                  // 4 KB
  float* exc_delta = (float*)(w8 + 275456);            // 4 KB
  unsigned long long* Hbits = (unsigned long long*)(w8 + 294912);  // 1 MB

  simi_gemm<<<dim3(NN / 128, EE / 128), 256, 0, stream>>>(x, y, hyper, simi);
  select_thr<<<dim3(EE), 256, 0, stream>>>(simi, thr, DE);
  build_h8<<<dim3(32, 8), 256, 0, stream>>>(simi, thr, Hbits, DVpart, H8);
  mode_exc<<<dim3(1), 256, 0, stream>>>(DE, modeInfo, exc_idx, exc_delta);
  g_mfma<<<dim3(2080), 256, 0, stream>>>(H8, DVpart, modeInfo, exc_idx, exc_delta,
                                         Hbits, out);
  hipMemcpyAsync(out + (size_t)NN * NN, x, (size_t)NN * DD * sizeof(float),
                 hipMemcpyDeviceToDevice, stream);
}